// Round 8
// baseline (257.357 us; speedup 1.0000x reference)
//
#include <hip/hip_runtime.h>

#define NN 8192
#define EE 256
#define KNH 32
#define NKEEP 4096
#define NCX 64
#define NCELL 4096

typedef unsigned long long u64;
typedef unsigned int u32;

// ws layout:
// part      @ 0      [2][32][256] f32   (65536)
// gm        @ 65536  [2][256] f32       ( 2048)
// cellcnt   @ 67584  [2][4096] int      (32768)
// cellstart @ 100352 [2][4097] int      (32800 alloc)
// fill      @ 133152 [2][4096] int      (32768)
// sc        @ 165920 [2][8192] float2   (131072)
// sj        @ 296992 [2][8192] int      (65536)   -> 362528 total

__device__ __forceinline__ int cellof(float v) {
    const int q = (int)floorf((v + 4.6f) * (64.0f / 9.2f));
    return min(max(q, 0), NCX - 1);
}

// column-sum partials for global mean; fused 2D cell count
__global__ void k_gm_partial(const float* __restrict__ x, const float* __restrict__ coords,
                             float* __restrict__ part, int* __restrict__ cellcnt) {
    const int b = blockIdx.y, chunk = blockIdx.x, t = threadIdx.x;
    const float* xp = x + ((size_t)b * NN + (size_t)chunk * 256) * EE + t;
    float s = 0.0f;
    for (int i = 0; i < 256; ++i) s += xp[(size_t)i * EE];
    part[((size_t)b * 32 + chunk) * EE + t] = s;

    const int i = chunk * 256 + t;
    const float xv = coords[(size_t)b * 2 * NN + i];
    const float yv = coords[(size_t)b * 2 * NN + NN + i];
    atomicAdd(&cellcnt[b * NCELL + cellof(xv) * NCX + cellof(yv)], 1);
}

__global__ void k_gm_final(const float* __restrict__ part, float* __restrict__ gm) {
    const int b = blockIdx.y, t = threadIdx.x;
    float s = 0.0f;
    for (int c = 0; c < 32; ++c) s += part[((size_t)b * 32 + c) * EE + t];
    gm[b * EE + t] = fabsf(s / (float)NN);
}

// prefix scan of 4096 cell counts (1 block of 1024 per batch)
__global__ void k_cell_scan(const int* __restrict__ cellcnt, int* __restrict__ start,
                            int* __restrict__ fill) {
    __shared__ int ps[1024];
    const int b = blockIdx.x, t = threadIdx.x;
    int v0 = cellcnt[b * NCELL + t * 4 + 0];
    int v1 = cellcnt[b * NCELL + t * 4 + 1];
    int v2 = cellcnt[b * NCELL + t * 4 + 2];
    int v3 = cellcnt[b * NCELL + t * 4 + 3];
    const int s = v0 + v1 + v2 + v3;
    ps[t] = s;
    __syncthreads();
    for (int d = 1; d < 1024; d <<= 1) {
        const int add = (t >= d) ? ps[t - d] : 0;
        __syncthreads();
        ps[t] += add;
        __syncthreads();
    }
    int run = ps[t] - s;
    start[b * (NCELL + 1) + t * 4 + 0] = run; fill[b * NCELL + t * 4 + 0] = run; run += v0;
    start[b * (NCELL + 1) + t * 4 + 1] = run; fill[b * NCELL + t * 4 + 1] = run; run += v1;
    start[b * (NCELL + 1) + t * 4 + 2] = run; fill[b * NCELL + t * 4 + 2] = run; run += v2;
    start[b * (NCELL + 1) + t * 4 + 3] = run; fill[b * NCELL + t * 4 + 3] = run; run += v3;
    if (t == 1023) start[b * (NCELL + 1) + NCELL] = run;
}

__global__ void k_scatter(const float* __restrict__ coords, int* __restrict__ fill,
                          float2* __restrict__ sc, int* __restrict__ sj) {
    const int b = blockIdx.y;
    const int i = blockIdx.x * 256 + threadIdx.x;
    const float xv = coords[(size_t)b * 2 * NN + i];
    const float yv = coords[(size_t)b * 2 * NN + NN + i];
    const int p = atomicAdd(&fill[b * NCELL + cellof(xv) * NCX + cellof(yv)], 1);
    sc[(size_t)b * NN + p] = make_float2(xv, yv);
    sj[(size_t)b * NN + p] = i;
}

__device__ __forceinline__ u64 shfl_xor_u64(u64 v, int m) {
    const u32 hi = (u32)__shfl_xor((int)(u32)(v >> 32), m);
    const u32 lo = (u32)__shfl_xor((int)(u32)v, m);
    return ((u64)hi << 32) | lo;
}

__device__ __forceinline__ u64 wave_min_u64(u64 h) {
#pragma unroll
    for (int s = 1; s < 64; s <<= 1) {
        const u64 o = shfl_xor_u64(h, s);
        h = (o < h) ? o : h;
    }
    return h;
}

// One wave per scatter-order point (cell-major order -> gather locality).
// Pass 1: full-scan per-lane min distance; T = 32nd smallest of 64 minima.
// Range: per x-slab, contiguous y-cell segment of the scatter array.
// Pass 2: survivors (d<=T) -> per-lane padded LDS slots -> compact -> u64
// bitonic sort -> exact top-32 by (d_bits, orig_j). Certificates -> fallback.
__global__ void __launch_bounds__(256) k_knn_dist(
        const float* __restrict__ x, const float* __restrict__ coords,
        const float* __restrict__ gm, const float2* __restrict__ sc,
        const int* __restrict__ sj, const int* __restrict__ start,
        float* __restrict__ ld_out) {
    __shared__ u64 slots[4][576];   // stride 9 per lane: bank-conflict-free
    __shared__ u64 comp[4][64];
    const int wg   = blockIdx.x;
    const int swz  = (wg & 7) * 512 + (wg >> 3);   // XCD-chunked, bijective
    const int b    = swz >> 11;
    const int pb   = swz & 2047;
    const int wid  = threadIdx.x >> 6;
    const int lane = threadIdx.x & 63;
    const int p    = pb * 4 + wid;

    const float2* scb = sc + (size_t)b * NN;
    const int*    sjb = sj + (size_t)b * NN;
    const float2 cp = scb[p];
    const int    i  = sjb[p];
    const float ci0 = cp.x, ci1 = cp.y;

    const float* cs0 = coords + (size_t)b * 2 * NN;
    const float* cs1 = cs0 + NN;

    // ---- pass 1: per-lane min distance over all 8192 ----
    float dmin = 1e30f;
#pragma unroll 4
    for (int t = 0; t < NN / 256; ++t) {
        const int j = t * 256 + (lane << 2);
        const float4 xa = *reinterpret_cast<const float4*>(cs0 + j);
        const float4 ya = *reinterpret_cast<const float4*>(cs1 + j);
        const float dx0 = ci0 - xa.x, dy0 = ci1 - ya.x;
        const float dx1 = ci0 - xa.y, dy1 = ci1 - ya.y;
        const float dx2 = ci0 - xa.z, dy2 = ci1 - ya.z;
        const float dx3 = ci0 - xa.w, dy3 = ci1 - ya.w;
        const float d0 = fmaf(dx0, dx0, dy0 * dy0);
        const float d1 = fmaf(dx1, dx1, dy1 * dy1);
        const float d2 = fmaf(dx2, dx2, dy2 * dy2);
        const float d3 = fmaf(dx3, dx3, dy3 * dy3);
        dmin = fminf(dmin, fminf(fminf(d0, d1), fminf(d2, d3)));
    }

    // ---- T = 32nd smallest of the 64 lane minima (u32 bitonic sort) ----
    u32 mk = __float_as_uint(dmin);
#pragma unroll
    for (int k = 2; k <= 64; k <<= 1) {
#pragma unroll
        for (int j = k >> 1; j > 0; j >>= 1) {
            const u32 o = (u32)__shfl_xor((int)mk, j);
            const bool keep_min = (((lane & j) == 0) == ((lane & k) == 0));
            const u32 mn = min(mk, o), mx = max(mk, o);
            mk = keep_min ? mn : mx;
        }
    }
    const u32 T = (u32)__shfl((int)mk, 31);

    // ---- 2D cell range (superset of the d<=T disk) ----
    const float s = sqrtf(__uint_as_float(T)) * 1.0002f + 1e-5f;
    const int xl = cellof(ci0 - s), xh = cellof(ci0 + s);
    const int yl = cellof(ci1 - s), yh = cellof(ci1 + s);
    const int* stb = start + b * (NCELL + 1);

    // ---- pass 2: survivors into per-lane slots over slab segments ----
    int cnt = 0;
    for (int xc = xl; xc <= xh; ++xc) {
        const int c0 = stb[xc * NCX + yl];
        const int c1 = stb[xc * NCX + yh + 1];
        for (int t0 = c0; t0 < c1; t0 += 64) {
            const int c = t0 + lane;
            const int cc = min(c, NN - 1);
            const float2 pt = scb[cc];
            const int    jj = sjb[cc];
            const float dx = ci0 - pt.x, dy = ci1 - pt.y;
            const u32 db = __float_as_uint(fmaf(dx, dx, dy * dy));
            const bool keep = (c < c1) && (db <= T);
            if (keep) {
                slots[wid][lane * 9 + (cnt & 7)] = ((u64)db << 32) | (u32)jj;
                ++cnt;
            }
        }
    }

    // ---- compact: exclusive scan of per-lane counts ----
    const int myc = min(cnt, 8);
    int scn = myc;
#pragma unroll
    for (int d = 1; d < 64; d <<= 1) {
        const int v = __shfl_up(scn, d);
        scn += (lane >= d) ? v : 0;
    }
    const int off   = scn - myc;
    const int total = __shfl(scn, 63);
    const bool ovf  = (total > 64) || (total < KNH) || __any(cnt > 8);

    for (int c2 = 0; c2 < myc; ++c2) {
        comp[wid][(off + c2) & 63] = slots[wid][lane * 9 + c2];
    }
    __syncthreads();

    // ---- bitonic sort (ascending) of up to 64 survivor keys ----
    u64 key = (lane < total) ? comp[wid][lane] : ~0ull;
#pragma unroll
    for (int k = 2; k <= 64; k <<= 1) {
#pragma unroll
        for (int j = k >> 1; j > 0; j >>= 1) {
            const u64 other = shfl_xor_u64(key, j);
            const bool keep_min = (((lane & j) == 0) == ((lane & k) == 0));
            const bool lt = (key < other);
            const u64 mn = lt ? key : other;
            const u64 mx = lt ? other : key;
            key = keep_min ? mn : mx;
        }
    }
    int jkeep = (int)(u32)key;   // lane m (m<32) holds m-th nearest index

    // ---- certificate fallback: exact 32-round argmin over the range ----
    if (ovf) {
        u64 minkeep = 0;
        for (int k = 0; k < KNH; ++k) {
            u64 best = ~0ull;
            for (int xc = xl; xc <= xh; ++xc) {
                const int c0 = stb[xc * NCX + yl];
                const int c1 = stb[xc * NCX + yh + 1];
                for (int t0 = c0; t0 < c1; t0 += 64) {
                    const int c = t0 + lane;
                    const int cc = min(c, NN - 1);
                    const float2 pt = scb[cc];
                    const int    jj = sjb[cc];
                    const float dx = ci0 - pt.x, dy = ci1 - pt.y;
                    const float d  = fmaf(dx, dx, dy * dy);
                    const u64 kk = ((u64)__float_as_uint(d) << 32) | (u32)jj;
                    if (c < c1 && kk >= minkeep && kk < best) best = kk;
                }
            }
            const u64 h = wave_min_u64(best);
            if (lane == k) jkeep = (int)(u32)h;
            minkeep = h + 1;
        }
    }

    // ---- gather 32 rows, f32 sum/sumsq (4 channels per lane) ----
    float s1[4] = {0.f, 0.f, 0.f, 0.f};
    float s2[4] = {0.f, 0.f, 0.f, 0.f};
    const float* xb = x + (size_t)b * NN * EE;
#pragma unroll 8
    for (int k = 0; k < KNH; ++k) {
        const int j = __shfl(jkeep, k);
        const float4 v = *reinterpret_cast<const float4*>(xb + (size_t)j * EE + (lane << 2));
        s1[0] += v.x; s2[0] += v.x * v.x;
        s1[1] += v.y; s2[1] += v.y * v.y;
        s1[2] += v.z; s2[2] += v.z * v.z;
        s1[3] += v.w; s2[3] += v.w * v.w;
    }

    const float* gmb = gm + b * EE;
    float tt = 0.f;
#pragma unroll
    for (int q = 0; q < 4; ++q) {
        const float sum = s1[q];
        float ssd = s2[q] - sum * sum * (1.0f / 32.0f);
        ssd = ssd > 0.f ? ssd : 0.f;
        const float ls = sqrtf(ssd * (1.0f / 31.0f));
        tt += ls / gmb[(lane << 2) + q];
    }
#pragma unroll
    for (int s2r = 1; s2r < 64; s2r <<= 1) tt += __shfl_xor(tt, s2r);

    if (lane == 0) ld_out[(size_t)b * NN + i] = tt;
}

// one wave per point: exact rank (desc, index tie-break) + direct row gather
__global__ void k_rank_gather(const float* __restrict__ x, const float* __restrict__ coords,
                              const float* __restrict__ ld,
                              float* __restrict__ x_out, float* __restrict__ c_out) {
    const int b    = blockIdx.y;
    const int wid  = threadIdx.x >> 6;
    const int lane = threadIdx.x & 63;
    const int i    = blockIdx.x * 4 + wid;
    const float* lb = ld + (size_t)b * NN;
    const float di = lb[i];
    int cnt = 0;
    for (int t = 0; t < NN / 64; ++t) {
        const int j = lane + t * 64;
        const float dj = lb[j];
        cnt += (dj > di || (dj == di && j < i)) ? 1 : 0;
    }
#pragma unroll
    for (int s = 1; s < 64; s <<= 1) cnt += __shfl_xor(cnt, s);

    if (cnt < NKEEP) {
        const float4 v = *reinterpret_cast<const float4*>(x + ((size_t)b * NN + i) * EE + (lane << 2));
        *reinterpret_cast<float4*>(x_out + ((size_t)b * NKEEP + cnt) * EE + (lane << 2)) = v;
        if (lane < 2) {
            c_out[((size_t)b * 2 + lane) * NKEEP + cnt] = coords[((size_t)b * 2 + lane) * NN + i];
        }
    }
}

extern "C" void kernel_launch(void* const* d_in, const int* in_sizes, int n_in,
                              void* d_out, int out_size, void* d_ws, size_t ws_size,
                              hipStream_t stream) {
    const float* x      = (const float*)d_in[0];
    const float* coords = (const float*)d_in[1];

    float* out    = (float*)d_out;
    float* x_out  = out;                 // [2][4096][256]
    float* c_out  = out + 2097152;       // [2][2][4096][1]
    float* ld_out = out + 2113536;       // [2][8192]

    char*   ws      = (char*)d_ws;
    float*  part    = (float*)(ws);
    float*  gm      = (float*)(ws + 65536);
    int*    cellcnt = (int*)  (ws + 67584);
    int*    start   = (int*)  (ws + 100352);
    int*    fill    = (int*)  (ws + 133152);
    float2* sc      = (float2*)(ws + 165920);
    int*    sj      = (int*)  (ws + 296992);

    hipMemsetAsync(cellcnt, 0, 2 * NCELL * sizeof(int), stream);
    k_gm_partial <<<dim3(32, 2), 256,  0, stream>>>(x, coords, part, cellcnt);
    k_gm_final   <<<dim3(1, 2),  256,  0, stream>>>(part, gm);
    k_cell_scan  <<<2,           1024, 0, stream>>>(cellcnt, start, fill);
    k_scatter    <<<dim3(32, 2), 256,  0, stream>>>(coords, fill, sc, sj);
    k_knn_dist   <<<4096,        256,  0, stream>>>(x, coords, gm, sc, sj, start, ld_out);
    k_rank_gather<<<dim3(2048, 2), 256, 0, stream>>>(x, coords, ld_out, x_out, c_out);
}

// Round 9
// 98.526 us; speedup vs baseline: 2.6121x; 2.6121x over previous
//
#include <hip/hip_runtime.h>

#define NN 8192
#define EE 256
#define KNH 32
#define NKEEP 4096
#define NCX 64
#define NCELL 4096
#define CNT_MIN 48

typedef unsigned long long u64;
typedef unsigned int u32;

// ws layout:
// part      @ 0      [2][32][256] f32   (65536)
// gm        @ 65536  [2][256] f32       ( 2048)
// cellcnt   @ 67584  [2][4096] int      (32768)
// cellstart @ 100352 [2][4097] int      (32800 alloc)
// fill      @ 133152 [2][4096] int      (32768)
// sc        @ 165920 [2][8192] float2   (131072)
// sj        @ 296992 [2][8192] int      (65536)   -> 362528 total

__device__ __forceinline__ int cellof(float v) {
    const int q = (int)floorf((v + 4.6f) * (64.0f / 9.2f));
    return min(max(q, 0), NCX - 1);
}

// column-sum partials for global mean; fused 2D cell count
__global__ void k_gm_partial(const float* __restrict__ x, const float* __restrict__ coords,
                             float* __restrict__ part, int* __restrict__ cellcnt) {
    const int b = blockIdx.y, chunk = blockIdx.x, t = threadIdx.x;
    const float* xp = x + ((size_t)b * NN + (size_t)chunk * 256) * EE + t;
    float s = 0.0f;
    for (int i = 0; i < 256; ++i) s += xp[(size_t)i * EE];
    part[((size_t)b * 32 + chunk) * EE + t] = s;

    const int i = chunk * 256 + t;
    const float xv = coords[(size_t)b * 2 * NN + i];
    const float yv = coords[(size_t)b * 2 * NN + NN + i];
    atomicAdd(&cellcnt[b * NCELL + cellof(xv) * NCX + cellof(yv)], 1);
}

__global__ void k_gm_final(const float* __restrict__ part, float* __restrict__ gm) {
    const int b = blockIdx.y, t = threadIdx.x;
    float s = 0.0f;
    for (int c = 0; c < 32; ++c) s += part[((size_t)b * 32 + c) * EE + t];
    gm[b * EE + t] = fabsf(s / (float)NN);
}

// prefix scan of 4096 cell counts (1 block of 1024 per batch)
__global__ void k_cell_scan(const int* __restrict__ cellcnt, int* __restrict__ start,
                            int* __restrict__ fill) {
    __shared__ int ps[1024];
    const int b = blockIdx.x, t = threadIdx.x;
    int v0 = cellcnt[b * NCELL + t * 4 + 0];
    int v1 = cellcnt[b * NCELL + t * 4 + 1];
    int v2 = cellcnt[b * NCELL + t * 4 + 2];
    int v3 = cellcnt[b * NCELL + t * 4 + 3];
    const int s = v0 + v1 + v2 + v3;
    ps[t] = s;
    __syncthreads();
    for (int d = 1; d < 1024; d <<= 1) {
        const int add = (t >= d) ? ps[t - d] : 0;
        __syncthreads();
        ps[t] += add;
        __syncthreads();
    }
    int run = ps[t] - s;
    start[b * (NCELL + 1) + t * 4 + 0] = run; fill[b * NCELL + t * 4 + 0] = run; run += v0;
    start[b * (NCELL + 1) + t * 4 + 1] = run; fill[b * NCELL + t * 4 + 1] = run; run += v1;
    start[b * (NCELL + 1) + t * 4 + 2] = run; fill[b * NCELL + t * 4 + 2] = run; run += v2;
    start[b * (NCELL + 1) + t * 4 + 3] = run; fill[b * NCELL + t * 4 + 3] = run; run += v3;
    if (t == 1023) start[b * (NCELL + 1) + NCELL] = run;
}

__global__ void k_scatter(const float* __restrict__ coords, int* __restrict__ fill,
                          float2* __restrict__ sc, int* __restrict__ sj) {
    const int b = blockIdx.y;
    const int i = blockIdx.x * 256 + threadIdx.x;
    const float xv = coords[(size_t)b * 2 * NN + i];
    const float yv = coords[(size_t)b * 2 * NN + NN + i];
    const int p = atomicAdd(&fill[b * NCELL + cellof(xv) * NCX + cellof(yv)], 1);
    sc[(size_t)b * NN + p] = make_float2(xv, yv);
    sj[(size_t)b * NN + p] = i;
}

__device__ __forceinline__ u64 shfl_xor_u64(u64 v, int m) {
    const u32 hi = (u32)__shfl_xor((int)(u32)(v >> 32), m);
    const u32 lo = (u32)__shfl_xor((int)(u32)v, m);
    return ((u64)hi << 32) | lo;
}

__device__ __forceinline__ u64 wave_min_u64(u64 h) {
#pragma unroll
    for (int s = 1; s < 64; s <<= 1) {
        const u64 o = shfl_xor_u64(h, s);
        h = (o < h) ? o : h;
    }
    return h;
}

// One wave per scatter-order point (cell-major order -> gather locality).
// Adaptive cell-square (doubling r) until >=CNT_MIN candidates; flattened
// wave-cooperative stream (lane l holds slab l bounds, 6-shfl slab search).
// Pass 1: per-lane min over stream -> T = 32nd smallest lane-min (bitonic).
// Pass 2: re-flatten sqrt(T)-box, ballot-compact survivors (d<=T) into wave
// buffer, u64 bitonic sort -> exact top-32 by (d_bits, orig_j).
// Certificates (base>64 | base<32) -> exact argmin fallback over the stream.
__global__ void __launch_bounds__(256) k_knn_dist(
        const float* __restrict__ x,
        const float* __restrict__ gm, const float2* __restrict__ sc,
        const int* __restrict__ sj, const int* __restrict__ start,
        float* __restrict__ ld_out) {
    __shared__ u64 comp[4][64];
    const int wg   = blockIdx.x;
    const int swz  = (wg & 7) * 512 + (wg >> 3);   // XCD-chunked, bijective
    const int b    = swz >> 11;
    const int pb   = swz & 2047;
    const int wid  = threadIdx.x >> 6;
    const int lane = threadIdx.x & 63;
    const int p    = pb * 4 + wid;

    const float2* scb = sc + (size_t)b * NN;
    const int*    sjb = sj + (size_t)b * NN;
    const int*    stb = start + b * (NCELL + 1);
    const float2 cp = scb[p];
    const int    i  = sjb[p];
    const float ci0 = cp.x, ci1 = cp.y;
    const int qx = cellof(ci0), qy = cellof(ci1);

    // ---- adaptive square: double r until count >= CNT_MIN ----
    int r = 1, xl, yl, yh, nsl;
    int myc0 = 0, mylen = 0;
    for (;;) {
        xl = max(qx - r, 0);
        const int xh = min(qx + r, NCX - 1);
        yl = max(qy - r, 0);
        yh = min(qy + r, NCX - 1);
        nsl = xh - xl + 1;
        int c0 = 0, c1 = 0;
        if (lane < nsl) {
            c0 = stb[(xl + lane) * NCX + yl];
            c1 = stb[(xl + lane) * NCX + yh + 1];
        }
        myc0 = c0; mylen = c1 - c0;
        int tot = mylen;
#pragma unroll
        for (int s = 1; s < 64; s <<= 1) tot += __shfl_xor(tot, s);
        if (tot >= CNT_MIN || r >= NCX) break;
        r <<= 1;
    }
    int incl = mylen;
#pragma unroll
    for (int d = 1; d < 64; d <<= 1) {
        const int v = __shfl_up(incl, d);
        incl += (lane >= d) ? v : 0;
    }
    int excl = incl - mylen;
    const int L1 = __shfl(incl, 63);

    // ---- pass 1: per-lane min over flattened stream ----
    float dmin = 1e30f;
    for (int g = 0; g < L1; g += 64) {
        const int gp = g + lane;
        int lo = 0, hi = nsl - 1;
#pragma unroll
        for (int st = 0; st < 6; ++st) {
            const int mid = (lo + hi + 1) >> 1;
            const int v = __shfl(excl, mid);
            const bool go = (v <= gp);
            lo = go ? mid : lo;
            hi = go ? hi : mid - 1;
        }
        const int cnd = __shfl(myc0, lo) + gp - __shfl(excl, lo);
        const int cc  = min(max(cnd, 0), NN - 1);
        const float2 pt = scb[cc];
        const float dx = ci0 - pt.x, dy = ci1 - pt.y;
        const float d  = fmaf(dx, dx, dy * dy);
        if (gp < L1) dmin = fminf(dmin, d);
    }

    // ---- T = 32nd smallest of the 64 lane minima (u32 bitonic sort) ----
    u32 mk = __float_as_uint(dmin);
#pragma unroll
    for (int k = 2; k <= 64; k <<= 1) {
#pragma unroll
        for (int j = k >> 1; j > 0; j >>= 1) {
            const u32 o = (u32)__shfl_xor((int)mk, j);
            const bool keep_min = (((lane & j) == 0) == ((lane & k) == 0));
            const u32 mn = min(mk, o), mx = max(mk, o);
            mk = keep_min ? mn : mx;
        }
    }
    const u32 T = (u32)__shfl((int)mk, 31);

    // ---- pass 2: flatten the sqrt(T)-box, ballot-compact survivors ----
    const float srad = sqrtf(__uint_as_float(T)) * 1.0002f + 1e-5f;
    xl = cellof(ci0 - srad);
    const int xh2 = cellof(ci0 + srad);
    yl = cellof(ci1 - srad);
    yh = cellof(ci1 + srad);
    nsl = xh2 - xl + 1;
    {
        int c0 = 0, c1 = 0;
        if (lane < nsl) {
            c0 = stb[(xl + lane) * NCX + yl];
            c1 = stb[(xl + lane) * NCX + yh + 1];
        }
        myc0 = c0; mylen = c1 - c0;
    }
    incl = mylen;
#pragma unroll
    for (int d = 1; d < 64; d <<= 1) {
        const int v = __shfl_up(incl, d);
        incl += (lane >= d) ? v : 0;
    }
    excl = incl - mylen;
    const int L2 = __shfl(incl, 63);

    const u64 lmask = (1ull << lane) - 1;
    int base = 0;
    for (int g = 0; g < L2; g += 64) {
        const int gp = g + lane;
        int lo = 0, hi = nsl - 1;
#pragma unroll
        for (int st = 0; st < 6; ++st) {
            const int mid = (lo + hi + 1) >> 1;
            const int v = __shfl(excl, mid);
            const bool go = (v <= gp);
            lo = go ? mid : lo;
            hi = go ? hi : mid - 1;
        }
        const int cnd = __shfl(myc0, lo) + gp - __shfl(excl, lo);
        const int cc  = min(max(cnd, 0), NN - 1);
        const float2 pt = scb[cc];
        const int    jj = sjb[cc];
        const float dx = ci0 - pt.x, dy = ci1 - pt.y;
        const u32 db = __float_as_uint(fmaf(dx, dx, dy * dy));
        const bool keep = (gp < L2) && (db <= T);
        const u64 m = __ballot(keep);
        const int pos = base + __popcll(m & lmask);
        base += __popcll(m);
        if (keep && pos < 64) comp[wid][pos] = ((u64)db << 32) | (u32)jj;
    }
    const bool ovf = (base > 64) || (base < KNH);

    // ---- bitonic sort (ascending) of up to 64 survivor keys ----
    u64 key = (lane < base) ? comp[wid][lane] : ~0ull;
#pragma unroll
    for (int k = 2; k <= 64; k <<= 1) {
#pragma unroll
        for (int j = k >> 1; j > 0; j >>= 1) {
            const u64 other = shfl_xor_u64(key, j);
            const bool keep_min = (((lane & j) == 0) == ((lane & k) == 0));
            const bool lt = (key < other);
            const u64 mn = lt ? key : other;
            const u64 mx = lt ? other : key;
            key = keep_min ? mn : mx;
        }
    }
    int jkeep = (int)(u32)key;   // lane m (m<32) holds m-th nearest index

    // ---- certificate fallback: exact 32-round argmin over the stream ----
    if (ovf) {
        u64 minkeep = 0;
        for (int k = 0; k < KNH; ++k) {
            u64 best = ~0ull;
            for (int g = 0; g < L2; g += 64) {
                const int gp = g + lane;
                int lo = 0, hi = nsl - 1;
#pragma unroll
                for (int st = 0; st < 6; ++st) {
                    const int mid = (lo + hi + 1) >> 1;
                    const int v = __shfl(excl, mid);
                    const bool go = (v <= gp);
                    lo = go ? mid : lo;
                    hi = go ? hi : mid - 1;
                }
                const int cnd = __shfl(myc0, lo) + gp - __shfl(excl, lo);
                const int cc  = min(max(cnd, 0), NN - 1);
                const float2 pt = scb[cc];
                const int    jj = sjb[cc];
                const float dx = ci0 - pt.x, dy = ci1 - pt.y;
                const float d  = fmaf(dx, dx, dy * dy);
                const u64 kk = ((u64)__float_as_uint(d) << 32) | (u32)jj;
                if (gp < L2 && kk >= minkeep && kk < best) best = kk;
            }
            const u64 h = wave_min_u64(best);
            if (lane == k) jkeep = (int)(u32)h;
            minkeep = h + 1;
        }
    }

    // ---- gather 32 rows, f32 sum/sumsq (4 channels per lane) ----
    float s1[4] = {0.f, 0.f, 0.f, 0.f};
    float s2[4] = {0.f, 0.f, 0.f, 0.f};
    const float* xb = x + (size_t)b * NN * EE;
#pragma unroll 8
    for (int k = 0; k < KNH; ++k) {
        const int j = __shfl(jkeep, k);
        const float4 v = *reinterpret_cast<const float4*>(xb + (size_t)j * EE + (lane << 2));
        s1[0] += v.x; s2[0] += v.x * v.x;
        s1[1] += v.y; s2[1] += v.y * v.y;
        s1[2] += v.z; s2[2] += v.z * v.z;
        s1[3] += v.w; s2[3] += v.w * v.w;
    }

    const float* gmb = gm + b * EE;
    float tt = 0.f;
#pragma unroll
    for (int q = 0; q < 4; ++q) {
        const float sum = s1[q];
        float ssd = s2[q] - sum * sum * (1.0f / 32.0f);
        ssd = ssd > 0.f ? ssd : 0.f;
        const float ls = sqrtf(ssd * (1.0f / 31.0f));
        tt += ls / gmb[(lane << 2) + q];
    }
#pragma unroll
    for (int s2r = 1; s2r < 64; s2r <<= 1) tt += __shfl_xor(tt, s2r);

    if (lane == 0) ld_out[(size_t)b * NN + i] = tt;
}

// one wave per point: exact rank (desc, index tie-break) + direct row gather
__global__ void k_rank_gather(const float* __restrict__ x, const float* __restrict__ coords,
                              const float* __restrict__ ld,
                              float* __restrict__ x_out, float* __restrict__ c_out) {
    const int b    = blockIdx.y;
    const int wid  = threadIdx.x >> 6;
    const int lane = threadIdx.x & 63;
    const int i    = blockIdx.x * 4 + wid;
    const float* lb = ld + (size_t)b * NN;
    const float di = lb[i];
    int cnt = 0;
    for (int t = 0; t < NN / 64; ++t) {
        const int j = lane + t * 64;
        const float dj = lb[j];
        cnt += (dj > di || (dj == di && j < i)) ? 1 : 0;
    }
#pragma unroll
    for (int s = 1; s < 64; s <<= 1) cnt += __shfl_xor(cnt, s);

    if (cnt < NKEEP) {
        const float4 v = *reinterpret_cast<const float4*>(x + ((size_t)b * NN + i) * EE + (lane << 2));
        *reinterpret_cast<float4*>(x_out + ((size_t)b * NKEEP + cnt) * EE + (lane << 2)) = v;
        if (lane < 2) {
            c_out[((size_t)b * 2 + lane) * NKEEP + cnt] = coords[((size_t)b * 2 + lane) * NN + i];
        }
    }
}

extern "C" void kernel_launch(void* const* d_in, const int* in_sizes, int n_in,
                              void* d_out, int out_size, void* d_ws, size_t ws_size,
                              hipStream_t stream) {
    const float* x      = (const float*)d_in[0];
    const float* coords = (const float*)d_in[1];

    float* out    = (float*)d_out;
    float* x_out  = out;                 // [2][4096][256]
    float* c_out  = out + 2097152;       // [2][2][4096][1]
    float* ld_out = out + 2113536;       // [2][8192]

    char*   ws      = (char*)d_ws;
    float*  part    = (float*)(ws);
    float*  gm      = (float*)(ws + 65536);
    int*    cellcnt = (int*)  (ws + 67584);
    int*    start   = (int*)  (ws + 100352);
    int*    fill    = (int*)  (ws + 133152);
    float2* sc      = (float2*)(ws + 165920);
    int*    sj      = (int*)  (ws + 296992);

    hipMemsetAsync(cellcnt, 0, 2 * NCELL * sizeof(int), stream);
    k_gm_partial <<<dim3(32, 2), 256,  0, stream>>>(x, coords, part, cellcnt);
    k_gm_final   <<<dim3(1, 2),  256,  0, stream>>>(part, gm);
    k_cell_scan  <<<2,           1024, 0, stream>>>(cellcnt, start, fill);
    k_scatter    <<<dim3(32, 2), 256,  0, stream>>>(coords, fill, sc, sj);
    k_knn_dist   <<<4096,        256,  0, stream>>>(x, gm, sc, sj, start, ld_out);
    k_rank_gather<<<dim3(2048, 2), 256, 0, stream>>>(x, coords, ld_out, x_out, c_out);
}